// Round 16
// baseline (93.981 us; speedup 1.0000x reference)
//
#include <hip/hip_runtime.h>
#include <stdint.h>

typedef _Float16 half8   __attribute__((ext_vector_type(8)));
typedef float    floatx4 __attribute__((ext_vector_type(4)));
typedef float    floatx16 __attribute__((ext_vector_type(16)));
typedef uint32_t uint4v  __attribute__((ext_vector_type(4)));

#define KDIM 4096
#define ODIM 11008
#define NG   32

__global__ void zero_out_kernel(float4* __restrict__ out) {
    out[(size_t)blockIdx.x * 256 + threadIdx.x] = float4{0.f, 0.f, 0.f, 0.f};
}

__device__ __forceinline__ uint32_t pk_f16(float a, float b) {
    return __builtin_bit_cast(uint32_t, __builtin_amdgcn_cvt_pkrtz(a, b));
}

// exact fp16 (1024+nibble) B fragment from one qweight dword; halves pair
// nibbles (j, j+4) — matches xh3's A pairing.
__device__ __forceinline__ half8 dq(uint32_t ud) {
    const uint4v bw = {
        ( ud         & 0x000F000Fu) | 0x64006400u,
        ((ud >> 4)   & 0x000F000Fu) | 0x64006400u,
        ((ud >> 8)   & 0x000F000Fu) | 0x64006400u,
        ((ud >> 12)  & 0x000F000Fu) | 0x64006400u};
    return __builtin_bit_cast(half8, bw);
}

// x fp32 [64][4096] -> f16 A-fragments for mfma_32x32x16: xh3[g][ks][mt][lane],
// lane = h*32 + (m&31), mt = m>>5, chunk c = h*8 + ks (k = c*8..c*8+7),
// dword d = (x_{c*8+d}, x_{c*8+d+4}). Plus rowsums xsumT[32][64].
__global__ __launch_bounds__(256) void cvt_x_kernel(
    const float4* __restrict__ x, uint4v* __restrict__ xh3,
    float* __restrict__ xsumT)
{
    const int i = blockIdx.x * 256 + threadIdx.x;   // chunk id 0..32767
    const float4 f0 = x[2 * i];
    const float4 f1 = x[2 * i + 1];
    const uint4v v = {pk_f16(f0.x, f1.x), pk_f16(f0.y, f1.y),
                      pk_f16(f0.z, f1.z), pk_f16(f0.w, f1.w)};
    const int m  = i >> 9, c = i & 511;
    const int g  = c >> 4, cg = c & 15, h = cg >> 3, ks = cg & 7;
    const int mt = m >> 5, ml = m & 31;
    xh3[((size_t)(g * 8 + ks) * 2 + mt) * 64 + h * 32 + ml] = v;

    float p = f0.x + f0.y + f0.z + f0.w + f1.x + f1.y + f1.z + f1.w;
    p += __shfl_xor(p, 1);
    p += __shfl_xor(p, 2);
    p += __shfl_xor(p, 4);
    p += __shfl_xor(p, 8);
    if ((threadIdx.x & 15) == 0) xsumT[g * 64 + m] = p;
}

// Block: 32 o-cols x half-K; 4 waves = 4 k-eighths (4 groups each), each wave
// covers 32 o x all 64 m via mfma_f32_32x32x16_f16 (2x MACs per fragment byte
// vs 16x16x32 -> x-stream halves to 176 MB). qweight unique per wave (2
// uint4/lane/group, dist-1 prefetch, rolled loop, NO main-loop barriers).
// Epilogue: 4-way LDS k-reduce + atomicAdd. Grid: 688 blocks.
__global__ __launch_bounds__(256, 2) void w4a16_kernel(
    const uint4v*   __restrict__ xh3,    // [32][8][2][64] uint4
    const uint4v*   __restrict__ qw,     // [11008][128] uint4
    const uint32_t* __restrict__ qz,     // [11008][4]
    const float*    __restrict__ sc,     // [11008][32] (fp32-upcast fp16)
    const float*    __restrict__ xsumT,  // [32][64]
    float*          __restrict__ out)    // [64][11008]
{
    __shared__ float red[4][2048];       // 32 KB

    const int t    = threadIdx.x;
    const int kw   = t >> 6;            // wave -> k-eighth (4 groups)
    const int lane = t & 63;
    const int h    = lane >> 5;         // lane half (B k-chunk set)
    const int ml   = lane & 31;         // o col (B n) / m row (A m)

    const int kb = blockIdx.x & 1;      // k-half (interleaved for L2 spread)
    const int ob = blockIdx.x >> 1;
    const int o0 = ob * 32;
    const int o  = o0 + ml;
    const int g0 = kb * 16 + kw * 4;    // first group of this wave

    // qweight: row o, group g chunks h*8..h*8+7 = uint4s g*4 + h*2 + {0,1}
    const uint4v* qwp = qw + (size_t)o * 128 + g0 * 4 + h * 2;
    const uint32_t zdw = qz[(size_t)o * 4 + (g0 >> 3)];
    const int zsh = (g0 & 7) * 4;
    const floatx4 sv = *reinterpret_cast<const floatx4*>(sc + (size_t)o * NG + g0);

    const uint4v* xp = xh3 + (size_t)g0 * 16 * 64 + lane;

    floatx16 acc[2] = {};               // [mt] 16 f32 each

    // dist-1 prefetch of the group's 2 qweight uint4s
    uint4v u0 = qwp[0], u1 = qwp[1];

    #pragma unroll 1
    for (int gi = 0; gi < 4; ++gi) {
        const uint4v c0 = u0, c1 = u1;
        if (gi + 1 < 4) { u0 = qwp[(gi + 1) * 4]; u1 = qwp[(gi + 1) * 4 + 1]; }

        const int   g   = g0 + gi;
        const float s   = sv[gi];
        const uint32_t zn = (zdw >> (zsh + gi * 4)) & 0xFu;
        const float czs = s * (1024.0f + (float)zn);

        // B fragments for 8 k-steps (shared across both m-tiles)
        half8 b[8];
        #pragma unroll
        for (int ks = 0; ks < 4; ++ks) { b[ks] = dq(c0[ks]); b[4 + ks] = dq(c1[ks]); }

        #pragma unroll
        for (int mt = 0; mt < 2; ++mt) {
            // A fragments: 8-deep MLP burst
            uint4v ax[8];
            #pragma unroll
            for (int ks = 0; ks < 8; ++ks)
                ax[ks] = xp[(size_t)(gi * 16 + ks * 2 + mt) * 64];

            floatx16 tmp = {};
            #pragma unroll
            for (int ks = 0; ks < 8; ++ks)
                tmp = __builtin_amdgcn_mfma_f32_32x32x16_f16(
                    __builtin_bit_cast(half8, ax[ks]), b[ks], tmp, 0, 0, 0);

            // fold scale + zero-point correction
            // C row = (r&3) + 8*(r>>2) + 4*h  (within mt*32)
            #pragma unroll
            for (int rr = 0; rr < 4; ++rr) {
                const floatx4 xsg = *reinterpret_cast<const floatx4*>(
                    xsumT + g * 64 + mt * 32 + rr * 8 + h * 4);
                #pragma unroll
                for (int j = 0; j < 4; ++j)
                    acc[mt][rr * 4 + j] += s * tmp[rr * 4 + j] - czs * xsg[j];
            }
        }
    }

    // ---- epilogue: 4-way k-reduce through LDS, then atomic accumulate ----
    #pragma unroll
    for (int mt = 0; mt < 2; ++mt)
        #pragma unroll
        for (int rr = 0; rr < 4; ++rr)
            #pragma unroll
            for (int j = 0; j < 4; ++j) {
                const int m = mt * 32 + rr * 8 + h * 4 + j;
                red[kw][m * 32 + ml] = acc[mt][rr * 4 + j];
            }
    __syncthreads();

    #pragma unroll
    for (int r = 0; r < 8; ++r) {
        const int i  = r * 256 + t;     // 0..2047
        const int m  = i >> 5, ol = i & 31;
        const float v = red[0][i] + red[1][i] + red[2][i] + red[3][i];
        atomicAdd(out + (size_t)m * ODIM + o0 + ol, v);
    }
}

extern "C" void kernel_launch(void* const* d_in, const int* in_sizes, int n_in,
                              void* d_out, int out_size, void* d_ws, size_t ws_size,
                              hipStream_t stream) {
    const float*    x       = (const float*)d_in[0];
    const uint32_t* qweight = (const uint32_t*)d_in[1];
    const uint32_t* qzeros  = (const uint32_t*)d_in[2];
    const float*    scales  = (const float*)d_in[3];
    float* out = (float*)d_out;

    uint4v* xh3   = (uint4v*)d_ws;                         // 512 KB
    float*  xsumT = (float*)((char*)d_ws + 512 * 1024);    // 8 KB

    cvt_x_kernel<<<dim3(128), dim3(256), 0, stream>>>((const float4*)x, xh3, xsumT);
    zero_out_kernel<<<dim3(688), dim3(256), 0, stream>>>((float4*)out);
    w4a16_kernel<<<dim3(688), dim3(256), 0, stream>>>(
        xh3, (const uint4v*)qweight, qzeros, scales, xsumT, out);
}